// Round 6
// baseline (5645.155 us; speedup 1.0000x reference)
//
#include <hip/hip_runtime.h>
#include <math.h>

// Problem constants
#define Bb 64
#define Tt 512
#define Ee 128
#define Hq 256
#define G3 768      // 3*H
#define KK 16

// GRU recurrence tuning: k-slabs held in VGPRs per thread (3 gates each)
#define WK 128
#define KS (Hq - WK)   // streamed k-slabs

// Workspace layout (in floats).  Budget: 256 MiB = 67,108,864 floats.
// h-states are written IN PLACE into the consumed xp rows (first 256 of 768).
#define OFF_WTF  0
#define OFF_WTB  196608                        // 768*256
#define OFF_XPF  393216
#define OFF_XPB  (OFF_XPF + 25165824)          // 32768*768
#define OFF_EM   (OFF_XPB + 25165824)
#define WS_FLOATS ((size_t)(OFF_EM + 524288))  // = 51,249,152 floats = 205 MB

// ---------------------------------------------------------------------------
// Repack w_hh (768x256, row=gate g, col=k) into k-quad layout:
//   wt[((k>>2)*768 + g)*4 + (k&3)] = w[g][k]
// so a float4 load at ((kq*768+g)*4) yields w[g][4kq..4kq+3].
__global__ __launch_bounds__(256) void transpose_whh(const float* __restrict__ w,
                                                     float* __restrict__ wt)
{
    const int idx = blockIdx.x * 256 + threadIdx.x;
    if (idx < G3 * Hq) {
        const int g = idx >> 8;        // gate row 0..767
        const int k = idx & 255;       // k 0..255
        wt[(((size_t)(k >> 2) * G3 + g) << 2) + (k & 3)] = w[idx];
    }
}

// ---------------------------------------------------------------------------
// Fused embedding-gather + input projection for both directions.
// xp[m][g] = sum_k embed[x[m]][k] * w_ih[g][k] + b_ih[g] + (g<512 ? b_hh[g] : 0)
// M=32768 rows, N=1536 (768 fwd | 768 bwd), K=128.  64x64 tile, 256 thr, 4x4/thr.
__global__ __launch_bounds__(256) void proj_kernel(
    const int* __restrict__ x, const float* __restrict__ embed,
    const float* __restrict__ wf, const float* __restrict__ wb,
    const float* __restrict__ bihf, const float* __restrict__ bhhf,
    const float* __restrict__ bihb, const float* __restrict__ bhhb,
    float* __restrict__ xpf, float* __restrict__ xpb)
{
    __shared__ float As[64][66];   // [k_local][mi]
    __shared__ float Bs[64][66];   // [k_local][ni]
    const int bi = blockIdx.x;
    const int mb = bi / 24, nb = bi % 24;
    const int m0 = mb * 64, n0 = nb * 64;
    const int tid = threadIdx.x;
    const int tx = tid & 15, ty = tid >> 4;
    float acc[4][4] = {};

    for (int kc = 0; kc < 128; kc += 64) {
        __syncthreads();
        // stage A (embedding rows, transposed into LDS)
        for (int it = 0; it < 4; ++it) {
            const int l  = it * 256 + tid;        // 0..1023
            const int mi = l >> 4;
            const int k4 = (l & 15) << 2;
            const int row = x[m0 + mi];
            const float4 v = *(const float4*)(embed + (size_t)row * Ee + kc + k4);
            As[k4 + 0][mi] = v.x; As[k4 + 1][mi] = v.y;
            As[k4 + 2][mi] = v.z; As[k4 + 3][mi] = v.w;
        }
        // stage B (w_ih rows for this gate tile, transposed)
        for (int it = 0; it < 4; ++it) {
            const int l  = it * 256 + tid;
            const int ni = l >> 4;
            const int k4 = (l & 15) << 2;
            const int g  = n0 + ni;
            const float* wsrc = (g < G3) ? (wf + (size_t)g * Ee)
                                         : (wb + (size_t)(g - G3) * Ee);
            const float4 v = *(const float4*)(wsrc + kc + k4);
            Bs[k4 + 0][ni] = v.x; Bs[k4 + 1][ni] = v.y;
            Bs[k4 + 2][ni] = v.z; Bs[k4 + 3][ni] = v.w;
        }
        __syncthreads();
        for (int k = 0; k < 64; ++k) {
            const float a0 = As[k][ty];      const float a1 = As[k][ty + 16];
            const float a2 = As[k][ty + 32]; const float a3 = As[k][ty + 48];
            const float b0 = Bs[k][tx];      const float b1 = Bs[k][tx + 16];
            const float b2 = Bs[k][tx + 32]; const float b3 = Bs[k][tx + 48];
            acc[0][0] += a0 * b0; acc[0][1] += a0 * b1; acc[0][2] += a0 * b2; acc[0][3] += a0 * b3;
            acc[1][0] += a1 * b0; acc[1][1] += a1 * b1; acc[1][2] += a1 * b2; acc[1][3] += a1 * b3;
            acc[2][0] += a2 * b0; acc[2][1] += a2 * b1; acc[2][2] += a2 * b2; acc[2][3] += a2 * b3;
            acc[3][0] += a3 * b0; acc[3][1] += a3 * b1; acc[3][2] += a3 * b2; acc[3][3] += a3 * b3;
        }
    }
#pragma unroll
    for (int i = 0; i < 4; ++i) {
        const int m = m0 + ty + 16 * i;
#pragma unroll
        for (int c = 0; c < 4; ++c) {
            const int g = n0 + tx + 16 * c;
            const float v = acc[i][c];
            if (g < G3) {
                const float bias = bihf[g] + (g < 2 * Hq ? bhhf[g] : 0.0f);
                xpf[(size_t)m * G3 + g] = v + bias;
            } else {
                const int g2 = g - G3;
                const float bias = bihb[g2] + (g2 < 2 * Hq ? bhhb[g2] : 0.0f);
                xpb[(size_t)m * G3 + g2] = v + bias;
            }
        }
    }
}

// ---------------------------------------------------------------------------
// GRU recurrence, NG=3 layout. One block per (dir,batch): 128 blocks x 256 thr.
// Thread j owns hidden unit j: computes r,z,n dots (256 MACs each) per step.
// Weights: k<WK in VGPRs (3*WK floats/thread), k>=WK streamed from L2 as
// float4 k-quads. h broadcast from LDS (double-buffered, 1 barrier/step).
// h[t] written in place into xp[t][0..255].
__global__ __launch_bounds__(256, 1)
__attribute__((amdgpu_waves_per_eu(1, 1)))
void gru_kernel(const float* __restrict__ wt0,
                float* __restrict__ xpf, float* __restrict__ xpb,
                const float* __restrict__ bhhf, const float* __restrict__ bhhb)
{
    __shared__ float sh_h[2][Hq];
    const int bid = blockIdx.x;
    const int dir = bid >> 6;
    const int b   = bid & 63;
    const int j   = threadIdx.x;           // hidden unit 0..255
    const float* wt = wt0 + (size_t)dir * (G3 * Hq);
    float* xp = (dir ? xpb : xpf) + (size_t)b * Tt * G3;

    // preload VGPR weights for k in [0, WK)
    float wr[WK], wz[WK], wn[WK];
#pragma unroll
    for (int kq = 0; kq < WK / 4; ++kq) {
        const float* base = wt + (((size_t)kq * G3 + j) << 2);
        const float4 vr = *(const float4*)(base);
        const float4 vz = *(const float4*)(base + Hq * 4);
        const float4 vn = *(const float4*)(base + 2 * Hq * 4);
        wr[4*kq+0] = vr.x; wr[4*kq+1] = vr.y; wr[4*kq+2] = vr.z; wr[4*kq+3] = vr.w;
        wz[4*kq+0] = vz.x; wz[4*kq+1] = vz.y; wz[4*kq+2] = vz.z; wz[4*kq+3] = vz.w;
        wn[4*kq+0] = vn.x; wn[4*kq+1] = vn.y; wn[4*kq+2] = vn.z; wn[4*kq+3] = vn.w;
    }

    const float bhn = (dir ? bhhb : bhhf)[2 * Hq + j];
    float hprev = 0.0f;
    sh_h[0][j] = 0.0f;
    __syncthreads();

    for (int ti = 0; ti < Tt; ++ti) {
        const int t  = dir ? (Tt - 1 - ti) : ti;
        const int rb = ti & 1;
        const float* hbuf = sh_h[rb];
        float* xrow = xp + (size_t)t * G3;

        // x parts (independent of h) -- issue early
        const float xr = xrow[j];
        const float xz = xrow[Hq + j];
        const float xn = xrow[2 * Hq + j];

        float ar = 0.0f, az = 0.0f, an = 0.0f;

        // VGPR-weight part: k in [0, WK)
#pragma unroll
        for (int kq = 0; kq < WK / 4; ++kq) {
            const float4 h4 = *(const float4*)(hbuf + 4 * kq);
            ar += h4.x * wr[4*kq+0] + h4.y * wr[4*kq+1] + h4.z * wr[4*kq+2] + h4.w * wr[4*kq+3];
            az += h4.x * wz[4*kq+0] + h4.y * wz[4*kq+1] + h4.z * wz[4*kq+2] + h4.w * wz[4*kq+3];
            an += h4.x * wn[4*kq+0] + h4.y * wn[4*kq+1] + h4.z * wn[4*kq+2] + h4.w * wn[4*kq+3];
        }

        // streamed part: k in [WK, 256), float4 k-quads from L2
        {
            const float* pw = wt + (((size_t)(WK / 4) * G3 + j) << 2);
#pragma unroll 4
            for (int kq = WK / 4; kq < Hq / 4; ++kq) {
                const float4 vr = *(const float4*)(pw);
                const float4 vz = *(const float4*)(pw + Hq * 4);
                const float4 vn = *(const float4*)(pw + 2 * Hq * 4);
                const float4 h4 = *(const float4*)(hbuf + 4 * kq);
                ar += h4.x * vr.x + h4.y * vr.y + h4.z * vr.z + h4.w * vr.w;
                az += h4.x * vz.x + h4.y * vz.y + h4.z * vz.z + h4.w * vz.w;
                an += h4.x * vn.x + h4.y * vn.y + h4.z * vn.z + h4.w * vn.w;
                pw += (size_t)G3 * 4;
            }
        }

        const float r = 1.0f / (1.0f + expf(-(xr + ar)));
        const float z = 1.0f / (1.0f + expf(-(xz + az)));
        const float n = tanhf(xn + r * (an + bhn));
        const float hnew = (1.0f - z) * n + z * hprev;
        hprev = hnew;
        sh_h[rb ^ 1][j] = hnew;
        xrow[j] = hnew;                    // in-place h store
        __syncthreads();
    }
}

// ---------------------------------------------------------------------------
// em[m][n] = sum_k hf[m][k]*fcw[n][k] + sum_k hb[m][k]*fcw[n][256+k] + fcb[n]
// hf/hb live in the first 256 floats of each 768-float xp row.
__global__ __launch_bounds__(256) void em_kernel(
    const float* __restrict__ hf, const float* __restrict__ hb,
    const float* __restrict__ fcw, const float* __restrict__ fcb,
    float* __restrict__ em)
{
    __shared__ float ht[16][129];
    __shared__ float wt2[16][129];
    const int m0 = blockIdx.x * 16;
    const int tid = threadIdx.x;
    const int r = tid >> 4, n = tid & 15;
    float acc = 0.0f;
    for (int s = 0; s < 2; ++s) {
        const float* src = s ? hb : hf;
        for (int kc = 0; kc < Hq; kc += 128) {
            __syncthreads();
            for (int it = 0; it < 8; ++it) {
                const int l = it * 256 + tid;
                const int rr = l >> 7, k = l & 127;
                ht[rr][k] = src[(size_t)(m0 + rr) * G3 + kc + k];
            }
            for (int it = 0; it < 8; ++it) {
                const int l = it * 256 + tid;
                const int rr = l >> 7, k = l & 127;
                wt2[rr][k] = fcw[(size_t)rr * (2 * Hq) + s * Hq + kc + k];
            }
            __syncthreads();
            for (int k = 0; k < 128; ++k)
                acc += ht[r][k] * wt2[n][k];
        }
    }
    em[(size_t)(m0 + r) * KK + n] = acc + fcb[n];
}

// ---------------------------------------------------------------------------
// Viterbi: one wave per batch. Lanes 0..15 = states. Backpointers in LDS.
__global__ __launch_bounds__(64) void viterbi_kernel(
    const float* __restrict__ em, const int* __restrict__ y,
    const float* __restrict__ tr, float* __restrict__ out)
{
    __shared__ unsigned char bps[(Tt - 1) * KK];
    __shared__ unsigned char msk[Tt];
    const int b = blockIdx.x;
    const int lane = threadIdx.x;
    if (lane >= KK) return;
    const int j = lane;
    float tc[KK];
#pragma unroll
    for (int i = 0; i < KK; ++i) tc[i] = tr[i * KK + j];
    const float* erow = em + (size_t)b * Tt * KK;
    const int* yrow = y + b * Tt;
    float s = tr[1 * KK + j] + erow[j];            // BOS row + em[:,0]
    if (j == 0) msk[0] = (unsigned char)(yrow[0] != 0);
    float e1 = erow[1 * KK + j];  int y1v = yrow[1];
    float e2 = erow[2 * KK + j];  int y2v = yrow[2];
    for (int t = 1; t < Tt; ++t) {
        const float e = e1; const int yt = y1v;
        e1 = e2; y1v = y2v;
        if (t + 2 < Tt) { e2 = erow[(size_t)(t + 2) * KK + j]; y2v = yrow[t + 2]; }
        float best = -3.0e38f; int arg = 0;
#pragma unroll
        for (int i = 0; i < KK; ++i) {
            const float si = __shfl(s, i, KK);
            const float c = si + tc[i];
            if (c > best) { best = c; arg = i; }   // strict >, first-max = argmax
        }
        best += e;
        const bool m = (yt != 0);
        if (m) s = best;
        bps[(t - 1) * KK + j] = m ? (unsigned char)arg : (unsigned char)j;
        if (j == 0) msk[t] = (unsigned char)m;
    }
    s += tr[j * KK + 2];                           // + trans[:,EOS]
    float bs = -3.0e38f; int bt = 0;
#pragma unroll
    for (int i = 0; i < KK; ++i) {
        const float si = __shfl(s, i, KK);
        if (si > bs) { bs = si; bt = i; }
    }
    if (j == 0) {
        out[b] = bs;
        float* path = out + Bb + (size_t)b * Tt;
        int tag = bt;
        path[Tt - 1] = msk[Tt - 1] ? (float)tag : 0.0f;
        for (int t = Tt - 2; t >= 0; --t) {
            tag = bps[t * KK + tag];
            path[t] = msk[t] ? (float)tag : 0.0f;
        }
    }
}

// Diagnostic fallback if workspace is too small: park ws_size in out[0..63].
__global__ void ws_report_kernel(float* out, float v)
{
    if (threadIdx.x < 64) out[threadIdx.x] = v;
}

// ---------------------------------------------------------------------------
extern "C" void kernel_launch(void* const* d_in, const int* in_sizes, int n_in,
                              void* d_out, int out_size, void* d_ws, size_t ws_size,
                              hipStream_t stream)
{
    const int*   x     = (const int*)d_in[0];
    const int*   y     = (const int*)d_in[1];
    const float* emb   = (const float*)d_in[2];
    const float* wihf  = (const float*)d_in[3];
    const float* whhf  = (const float*)d_in[4];
    const float* bihf  = (const float*)d_in[5];
    const float* bhhf  = (const float*)d_in[6];
    const float* wihb  = (const float*)d_in[7];
    const float* whhb  = (const float*)d_in[8];
    const float* bihb  = (const float*)d_in[9];
    const float* bhhb  = (const float*)d_in[10];
    const float* fcw   = (const float*)d_in[11];
    const float* fcb   = (const float*)d_in[12];
    const float* trans = (const float*)d_in[13];
    float* out = (float*)d_out;
    float* ws  = (float*)d_ws;

    if (ws_size < WS_FLOATS * sizeof(float)) {
        ws_report_kernel<<<1, 64, 0, stream>>>(out, (float)ws_size);
        return;
    }

    transpose_whh<<<768, 256, 0, stream>>>(whhf, ws + OFF_WTF);
    transpose_whh<<<768, 256, 0, stream>>>(whhb, ws + OFF_WTB);
    proj_kernel<<<12288, 256, 0, stream>>>(x, emb, wihf, wihb,
                                           bihf, bhhf, bihb, bhhb,
                                           ws + OFF_XPF, ws + OFF_XPB);
    gru_kernel<<<128, 256, 0, stream>>>(ws + OFF_WTF, ws + OFF_XPF, ws + OFF_XPB,
                                        bhhf, bhhb);
    em_kernel<<<2048, 256, 0, stream>>>(ws + OFF_XPF, ws + OFF_XPB, fcw, fcb,
                                        ws + OFF_EM);
    viterbi_kernel<<<64, 64, 0, stream>>>(ws + OFF_EM, y, trans, out);
}

// Round 7
// 2718.939 us; speedup vs baseline: 2.0762x; 2.0762x over previous
//
#include <hip/hip_runtime.h>
#include <math.h>

// Problem constants
#define Bb 64
#define Tt 512
#define Ee 128
#define Hq 256
#define G3 768      // 3*H
#define KK 16

// GRU tuning: per-thread k-range = 128 (half), as 32 quads:
//   RQ quads in VGPRs, LQ quads in LDS, rest streamed from L2.
#define THR 512
#define RQ 12
#define LQ 2
#define NSQ (32 - RQ - LQ)   // 18 streamed quads

// Workspace layout (in floats).  Budget: 256 MiB = 67,108,864 floats.
// h-states are written IN PLACE into the consumed xp rows (first 256 of 768).
#define OFF_WTF  0
#define OFF_WTB  196608                        // 768*256
#define OFF_XPF  393216
#define OFF_XPB  (OFF_XPF + 25165824)          // 32768*768
#define OFF_EM   (OFF_XPB + 25165824)
#define WS_FLOATS ((size_t)(OFF_EM + 524288))  // = 51,249,152 floats = 205 MB

// ---------------------------------------------------------------------------
// Repack w_hh (768x256, row g3 = gate*256+j, col k) into quad-gate layout:
//   wt[ ((Q*3 + gate)*256 + j)*4 + e ] = w[g3][4Q+e],  Q = k>>2, e = k&3
// so the float4 at index (Q*3+gate)*256+j holds w[gate,j][4Q..4Q+3],
// and consecutive j are consecutive float4s (coalesced).
__global__ __launch_bounds__(256) void transpose_whh(const float* __restrict__ w,
                                                     float* __restrict__ wt)
{
    const int idx = blockIdx.x * 256 + threadIdx.x;
    if (idx < G3 * Hq) {
        const int g3 = idx >> 8;       // 0..767
        const int k  = idx & 255;      // 0..255
        const int gate = g3 >> 8;      // 0..2
        const int j    = g3 & 255;
        const int Q = k >> 2, e = k & 3;
        wt[(size_t)(((Q * 3 + gate) << 8) + j) * 4 + e] = w[idx];
    }
}

// ---------------------------------------------------------------------------
// Fused embedding-gather + input projection for both directions.
// xp[m][g] = sum_k embed[x[m]][k] * w_ih[g][k] + b_ih[g] + (g<512 ? b_hh[g] : 0)
__global__ __launch_bounds__(256) void proj_kernel(
    const int* __restrict__ x, const float* __restrict__ embed,
    const float* __restrict__ wf, const float* __restrict__ wb,
    const float* __restrict__ bihf, const float* __restrict__ bhhf,
    const float* __restrict__ bihb, const float* __restrict__ bhhb,
    float* __restrict__ xpf, float* __restrict__ xpb)
{
    __shared__ float As[64][66];   // [k_local][mi]
    __shared__ float Bs[64][66];   // [k_local][ni]
    const int bi = blockIdx.x;
    const int mb = bi / 24, nb = bi % 24;
    const int m0 = mb * 64, n0 = nb * 64;
    const int tid = threadIdx.x;
    const int tx = tid & 15, ty = tid >> 4;
    float acc[4][4] = {};

    for (int kc = 0; kc < 128; kc += 64) {
        __syncthreads();
        for (int it = 0; it < 4; ++it) {
            const int l  = it * 256 + tid;
            const int mi = l >> 4;
            const int k4 = (l & 15) << 2;
            const int row = x[m0 + mi];
            const float4 v = *(const float4*)(embed + (size_t)row * Ee + kc + k4);
            As[k4 + 0][mi] = v.x; As[k4 + 1][mi] = v.y;
            As[k4 + 2][mi] = v.z; As[k4 + 3][mi] = v.w;
        }
        for (int it = 0; it < 4; ++it) {
            const int l  = it * 256 + tid;
            const int ni = l >> 4;
            const int k4 = (l & 15) << 2;
            const int g  = n0 + ni;
            const float* wsrc = (g < G3) ? (wf + (size_t)g * Ee)
                                         : (wb + (size_t)(g - G3) * Ee);
            const float4 v = *(const float4*)(wsrc + kc + k4);
            Bs[k4 + 0][ni] = v.x; Bs[k4 + 1][ni] = v.y;
            Bs[k4 + 2][ni] = v.z; Bs[k4 + 3][ni] = v.w;
        }
        __syncthreads();
        for (int k = 0; k < 64; ++k) {
            const float a0 = As[k][ty];      const float a1 = As[k][ty + 16];
            const float a2 = As[k][ty + 32]; const float a3 = As[k][ty + 48];
            const float b0 = Bs[k][tx];      const float b1 = Bs[k][tx + 16];
            const float b2 = Bs[k][tx + 32]; const float b3 = Bs[k][tx + 48];
            acc[0][0] += a0 * b0; acc[0][1] += a0 * b1; acc[0][2] += a0 * b2; acc[0][3] += a0 * b3;
            acc[1][0] += a1 * b0; acc[1][1] += a1 * b1; acc[1][2] += a1 * b2; acc[1][3] += a1 * b3;
            acc[2][0] += a2 * b0; acc[2][1] += a2 * b1; acc[2][2] += a2 * b2; acc[2][3] += a2 * b3;
            acc[3][0] += a3 * b0; acc[3][1] += a3 * b1; acc[3][2] += a3 * b2; acc[3][3] += a3 * b3;
        }
    }
#pragma unroll
    for (int i = 0; i < 4; ++i) {
        const int m = m0 + ty + 16 * i;
#pragma unroll
        for (int c = 0; c < 4; ++c) {
            const int g = n0 + tx + 16 * c;
            const float v = acc[i][c];
            if (g < G3) {
                const float bias = bihf[g] + (g < 2 * Hq ? bhhf[g] : 0.0f);
                xpf[(size_t)m * G3 + g] = v + bias;
            } else {
                const int g2 = g - G3;
                const float bias = bihb[g2] + (g2 < 2 * Hq ? bhhb[g2] : 0.0f);
                xpb[(size_t)m * G3 + g2] = v + bias;
            }
        }
    }
}

// ---------------------------------------------------------------------------
// GRU recurrence, split-k layout. One block per (dir,b): 128 blocks x 512 thr
// (8 waves, 2 waves/SIMD). Thread (j = tid&255, half = tid>>8) computes the
// r,z,n partial dots of hidden unit j over k in [half*128, half*128+128).
// Weights: RQ quads/thread in VGPRs (144 fl), LQ quads in LDS (48 KB staged
// once), NSQ quads streamed from L2 each step. h broadcast from LDS.
// Cross-half reduce via LDS; combine by tid<256. Two barriers/step.
__global__ __launch_bounds__(THR, 1)
__attribute__((amdgpu_waves_per_eu(2, 2)))
void gru_kernel(const float* __restrict__ wtq0,
                float* __restrict__ xpf, float* __restrict__ xpb,
                const float* __restrict__ bhhf, const float* __restrict__ bhhb)
{
    __shared__ float sh_h[2][Hq];              // 2 KB (double-buffered h)
    __shared__ float sh_p[2][3][Hq];           // 6 KB (partial sums)
    __shared__ float4 sh_w[2 * LQ * 3][Hq];    // 48 KB (LDS weight cache)

    const int bid  = blockIdx.x;
    const int dir  = bid >> 6;
    const int b    = bid & 63;
    const int tid  = threadIdx.x;
    const int j    = tid & 255;
    const int half = tid >> 8;

    const float4* wtq = (const float4*)(wtq0 + (size_t)dir * (G3 * Hq));
    float* xp = (dir ? xpb : xpf) + (size_t)b * Tt * G3;

    // VGPR-resident weights: quads q in [0, RQ)
    float wrv[4 * RQ], wzv[4 * RQ], wnv[4 * RQ];
#pragma unroll
    for (int q = 0; q < RQ; ++q) {
        const int Q = half * 32 + q;
        const float4 vr = wtq[(Q * 3 + 0) * Hq + j];
        const float4 vz = wtq[(Q * 3 + 1) * Hq + j];
        const float4 vn = wtq[(Q * 3 + 2) * Hq + j];
        wrv[4*q]=vr.x; wrv[4*q+1]=vr.y; wrv[4*q+2]=vr.z; wrv[4*q+3]=vr.w;
        wzv[4*q]=vz.x; wzv[4*q+1]=vz.y; wzv[4*q+2]=vz.z; wzv[4*q+3]=vz.w;
        wnv[4*q]=vn.x; wnv[4*q+1]=vn.y; wnv[4*q+2]=vn.z; wnv[4*q+3]=vn.w;
    }

    // Stage LDS weight cache: rows (half_w*LQ + ql)*3 + gate, 2*LQ*3*256 float4
    for (int idx = tid; idx < 2 * LQ * 3 * Hq; idx += THR) {
        const int row = idx >> 8;          // 0 .. 2*LQ*3-1
        const int jj  = idx & 255;
        const int gate = row % 3;
        const int qg   = row / 3;          // 0 .. 2*LQ-1
        const int hw   = qg / LQ;
        const int ql   = qg % LQ;
        const int Q    = hw * 32 + RQ + ql;
        sh_w[row][jj] = wtq[(Q * 3 + gate) * Hq + jj];
    }

    const float bhn = (dir ? bhhb : bhhf)[2 * Hq + j];   // used by tid<256
    float hprev = 0.0f;
    if (tid < Hq) sh_h[0][tid] = 0.0f;
    __syncthreads();

    int cur = 0;
    for (int ti = 0; ti < Tt; ++ti) {
        const int t = dir ? (Tt - 1 - ti) : ti;
        float* xrow = xp + (size_t)t * G3;

        // prefetch x parts (combiner threads) -- hides under the dot phase
        float xr = 0.f, xz = 0.f, xn = 0.f;
        if (tid < Hq) {
            xr = xrow[tid];
            xz = xrow[Hq + tid];
            xn = xrow[2 * Hq + tid];
        }

        const float4* hb4 = (const float4*)(sh_h[cur] + half * 128);
        float ar = 0.0f, az = 0.0f, an = 0.0f;

        // 1) VGPR-resident quads
#pragma unroll
        for (int q = 0; q < RQ; ++q) {
            const float4 h4 = hb4[q];
            ar += h4.x*wrv[4*q] + h4.y*wrv[4*q+1] + h4.z*wrv[4*q+2] + h4.w*wrv[4*q+3];
            az += h4.x*wzv[4*q] + h4.y*wzv[4*q+1] + h4.z*wzv[4*q+2] + h4.w*wzv[4*q+3];
            an += h4.x*wnv[4*q] + h4.y*wnv[4*q+1] + h4.z*wnv[4*q+2] + h4.w*wnv[4*q+3];
        }
        // 2) LDS-cached quads
#pragma unroll
        for (int ql = 0; ql < LQ; ++ql) {
            const float4 h4 = hb4[RQ + ql];
            const int row = (half * LQ + ql) * 3;
            const float4 vr = sh_w[row + 0][j];
            const float4 vz = sh_w[row + 1][j];
            const float4 vn = sh_w[row + 2][j];
            ar += h4.x*vr.x + h4.y*vr.y + h4.z*vr.z + h4.w*vr.w;
            az += h4.x*vz.x + h4.y*vz.y + h4.z*vz.z + h4.w*vz.w;
            an += h4.x*vn.x + h4.y*vn.y + h4.z*vn.z + h4.w*vn.w;
        }
        // 3) streamed quads from L2
        {
            const float4* pw = wtq + ((half * 32 + RQ + LQ) * 3) * Hq + j;
#pragma unroll 3
            for (int qs = 0; qs < NSQ; ++qs) {
                const float4 vr = pw[0];
                const float4 vz = pw[Hq];
                const float4 vn = pw[2 * Hq];
                const float4 h4 = hb4[RQ + LQ + qs];
                ar += h4.x*vr.x + h4.y*vr.y + h4.z*vr.z + h4.w*vr.w;
                az += h4.x*vz.x + h4.y*vz.y + h4.z*vz.z + h4.w*vz.w;
                an += h4.x*vn.x + h4.y*vn.y + h4.z*vn.z + h4.w*vn.w;
                pw += 3 * Hq;
            }
        }

        sh_p[half][0][j] = ar;
        sh_p[half][1][j] = az;
        sh_p[half][2][j] = an;
        __syncthreads();

        if (tid < Hq) {
            const float far_ = sh_p[0][0][tid] + sh_p[1][0][tid];
            const float faz_ = sh_p[0][1][tid] + sh_p[1][1][tid];
            const float fan_ = sh_p[0][2][tid] + sh_p[1][2][tid];
            const float r = 1.0f / (1.0f + expf(-(xr + far_)));
            const float z = 1.0f / (1.0f + expf(-(xz + faz_)));
            const float n = tanhf(xn + r * (fan_ + bhn));
            const float hnew = (1.0f - z) * n + z * hprev;
            hprev = hnew;
            sh_h[cur ^ 1][tid] = hnew;
            xrow[tid] = hnew;              // in-place h store
        }
        __syncthreads();
        cur ^= 1;
    }
}

// ---------------------------------------------------------------------------
// em[m][n] = sum_k hf[m][k]*fcw[n][k] + sum_k hb[m][k]*fcw[n][256+k] + fcb[n]
// hf/hb live in the first 256 floats of each 768-float xp row.
__global__ __launch_bounds__(256) void em_kernel(
    const float* __restrict__ hf, const float* __restrict__ hb,
    const float* __restrict__ fcw, const float* __restrict__ fcb,
    float* __restrict__ em)
{
    __shared__ float ht[16][129];
    __shared__ float wt2[16][129];
    const int m0 = blockIdx.x * 16;
    const int tid = threadIdx.x;
    const int r = tid >> 4, n = tid & 15;
    float acc = 0.0f;
    for (int s = 0; s < 2; ++s) {
        const float* src = s ? hb : hf;
        for (int kc = 0; kc < Hq; kc += 128) {
            __syncthreads();
            for (int it = 0; it < 8; ++it) {
                const int l = it * 256 + tid;
                const int rr = l >> 7, k = l & 127;
                ht[rr][k] = src[(size_t)(m0 + rr) * G3 + kc + k];
            }
            for (int it = 0; it < 8; ++it) {
                const int l = it * 256 + tid;
                const int rr = l >> 7, k = l & 127;
                wt2[rr][k] = fcw[(size_t)rr * (2 * Hq) + s * Hq + kc + k];
            }
            __syncthreads();
            for (int k = 0; k < 128; ++k)
                acc += ht[r][k] * wt2[n][k];
        }
    }
    em[(size_t)(m0 + r) * KK + n] = acc + fcb[n];
}

// ---------------------------------------------------------------------------
// Viterbi: one wave per batch. Lanes 0..15 = states. Backpointers in LDS.
__global__ __launch_bounds__(64) void viterbi_kernel(
    const float* __restrict__ em, const int* __restrict__ y,
    const float* __restrict__ tr, float* __restrict__ out)
{
    __shared__ unsigned char bps[(Tt - 1) * KK];
    __shared__ unsigned char msk[Tt];
    const int b = blockIdx.x;
    const int lane = threadIdx.x;
    if (lane >= KK) return;
    const int j = lane;
    float tc[KK];
#pragma unroll
    for (int i = 0; i < KK; ++i) tc[i] = tr[i * KK + j];
    const float* erow = em + (size_t)b * Tt * KK;
    const int* yrow = y + b * Tt;
    float s = tr[1 * KK + j] + erow[j];            // BOS row + em[:,0]
    if (j == 0) msk[0] = (unsigned char)(yrow[0] != 0);
    float e1 = erow[1 * KK + j];  int y1v = yrow[1];
    float e2 = erow[2 * KK + j];  int y2v = yrow[2];
    for (int t = 1; t < Tt; ++t) {
        const float e = e1; const int yt = y1v;
        e1 = e2; y1v = y2v;
        if (t + 2 < Tt) { e2 = erow[(size_t)(t + 2) * KK + j]; y2v = yrow[t + 2]; }
        float best = -3.0e38f; int arg = 0;
#pragma unroll
        for (int i = 0; i < KK; ++i) {
            const float si = __shfl(s, i, KK);
            const float c = si + tc[i];
            if (c > best) { best = c; arg = i; }   // strict >, first-max = argmax
        }
        best += e;
        const bool m = (yt != 0);
        if (m) s = best;
        bps[(t - 1) * KK + j] = m ? (unsigned char)arg : (unsigned char)j;
        if (j == 0) msk[t] = (unsigned char)m;
    }
    s += tr[j * KK + 2];                           // + trans[:,EOS]
    float bs = -3.0e38f; int bt = 0;
#pragma unroll
    for (int i = 0; i < KK; ++i) {
        const float si = __shfl(s, i, KK);
        if (si > bs) { bs = si; bt = i; }
    }
    if (j == 0) {
        out[b] = bs;
        float* path = out + Bb + (size_t)b * Tt;
        int tag = bt;
        path[Tt - 1] = msk[Tt - 1] ? (float)tag : 0.0f;
        for (int t = Tt - 2; t >= 0; --t) {
            tag = bps[t * KK + tag];
            path[t] = msk[t] ? (float)tag : 0.0f;
        }
    }
}

// Diagnostic fallback if workspace is too small: park ws_size in out[0..63].
__global__ void ws_report_kernel(float* out, float v)
{
    if (threadIdx.x < 64) out[threadIdx.x] = v;
}

// ---------------------------------------------------------------------------
extern "C" void kernel_launch(void* const* d_in, const int* in_sizes, int n_in,
                              void* d_out, int out_size, void* d_ws, size_t ws_size,
                              hipStream_t stream)
{
    const int*   x     = (const int*)d_in[0];
    const int*   y     = (const int*)d_in[1];
    const float* emb   = (const float*)d_in[2];
    const float* wihf  = (const float*)d_in[3];
    const float* whhf  = (const float*)d_in[4];
    const float* bihf  = (const float*)d_in[5];
    const float* bhhf  = (const float*)d_in[6];
    const float* wihb  = (const float*)d_in[7];
    const float* whhb  = (const float*)d_in[8];
    const float* bihb  = (const float*)d_in[9];
    const float* bhhb  = (const float*)d_in[10];
    const float* fcw   = (const float*)d_in[11];
    const float* fcb   = (const float*)d_in[12];
    const float* trans = (const float*)d_in[13];
    float* out = (float*)d_out;
    float* ws  = (float*)d_ws;

    if (ws_size < WS_FLOATS * sizeof(float)) {
        ws_report_kernel<<<1, 64, 0, stream>>>(out, (float)ws_size);
        return;
    }

    transpose_whh<<<768, 256, 0, stream>>>(whhf, ws + OFF_WTF);
    transpose_whh<<<768, 256, 0, stream>>>(whhb, ws + OFF_WTB);
    proj_kernel<<<12288, 256, 0, stream>>>(x, emb, wihf, wihb,
                                           bihf, bhhf, bihb, bhhb,
                                           ws + OFF_XPF, ws + OFF_XPB);
    gru_kernel<<<128, THR, 0, stream>>>(ws + OFF_WTF, ws + OFF_XPF, ws + OFF_XPB,
                                        bhhf, bhhb);
    em_kernel<<<2048, 256, 0, stream>>>(ws + OFF_XPF, ws + OFF_XPB, fcw, fcb,
                                        ws + OFF_EM);
    viterbi_kernel<<<64, 64, 0, stream>>>(ws + OFF_EM, y, trans, out);
}